// Round 8
// baseline (542.278 us; speedup 1.0000x reference)
//
#include <hip/hip_runtime.h>
#include <hip/hip_bf16.h>
#include <hip/hip_cooperative_groups.h>

namespace cg = cooperative_groups;

namespace {

constexpr int S = 2048;
constexpr int D = 64;
constexpr int NT = S / 32;   // 64 j-tiles
// 64^-0.5 * log2(e) folded into the Q cast: exp(q.k/8) == exp2((q*QSCALE).k)
constexpr float QSCALE = 0.125f * 1.4426950408889634f;

typedef __bf16 bf16x8 __attribute__((ext_vector_type(8)));
typedef float f32x16 __attribute__((ext_vector_type(16)));
typedef unsigned int uint32x4 __attribute__((ext_vector_type(4)));

#if __has_builtin(__builtin_amdgcn_exp2f)
__device__ __forceinline__ float fexp2(float x) { return __builtin_amdgcn_exp2f(x); }
#else
__device__ __forceinline__ float fexp2(float x) { return exp2f(x); }
#endif

__device__ __forceinline__ bf16x8 cvt8s(float4 a, float4 b, float s) {
    bf16x8 f;
    f[0] = (__bf16)(a.x * s); f[1] = (__bf16)(a.y * s);
    f[2] = (__bf16)(a.z * s); f[3] = (__bf16)(a.w * s);
    f[4] = (__bf16)(b.x * s); f[5] = (__bf16)(b.y * s);
    f[6] = (__bf16)(b.z * s); f[7] = (__bf16)(b.w * s);
    return f;
}
__device__ __forceinline__ bf16x8 cvt8(float4 a, float4 b) {
    bf16x8 f;
    f[0] = (__bf16)a.x; f[1] = (__bf16)a.y;
    f[2] = (__bf16)a.z; f[3] = (__bf16)a.w;
    f[4] = (__bf16)b.x; f[5] = (__bf16)b.y;
    f[6] = (__bf16)b.z; f[7] = (__bf16)b.w;
    return f;
}
__device__ __forceinline__ unsigned int pkbf(float lo, float hi) {
    unsigned int a = (unsigned int)__builtin_bit_cast(unsigned short, (__bf16)lo);
    unsigned int b = (unsigned int)__builtin_bit_cast(unsigned short, (__bf16)hi);
    return a | (b << 16);
}

} // namespace

// ================= Cooperative kernel =================
// Phase 0: each block converts its head's j-slice (128 rows) of K -> bf16
// [j][d] and V -> bf16 transposed [d][j] into d_ws. grid.sync(). Then the
// verified round-7 two-pass pipeline with bf16 16B-memcpy staging.
__global__ void __launch_bounds__(256, 4)
attn_coop(const float* __restrict__ qg, const float* __restrict__ kg,
          const float* __restrict__ vg, const int* __restrict__ mg,
          float* __restrict__ og, float* __restrict__ ag,
          unsigned short* __restrict__ kb, unsigned short* __restrict__ vt)
{
    __shared__ bf16x8 kstage[3][256];        // K tile [j=32][8 d-chunks], XOR slot
    __shared__ bf16x8 vstage[3][256];        // V tile transposed [d=64][4 j-chunks]
    __shared__ unsigned int mlds[64];        // mask bitmap: bit j&31 of word j>>5

    const int tid  = threadIdx.x;
    const int lane = tid & 63;
    const int w    = tid >> 6;
    const int l31  = lane & 31;
    const int h2   = lane >> 5;

    // XCD-aware remap: 8 contiguous heads per XCD -> K/V L2-resident
    const int wid = (blockIdx.x & 7) * 128 + (blockIdx.x >> 3);
    const int bh  = wid >> 4;
    const int q0  = ((wid & 15) * 4 + w) * 32;
    const int b   = bh >> 4;

    // ---- Phase 0: bf16 conversion of this block's j-slice ----
    {
        const int slice = wid & 15;
        const float* kgh = kg + (size_t)bh * S * D;
        const float* vgh = vg + (size_t)bh * S * D;
        unsigned short* kbh = kb + (size_t)bh * S * D;
        unsigned short* vth = vt + (size_t)bh * S * D;
#pragma unroll
        for (int r = 0; r < 4; ++r) {
            const int row = slice * 128 + r * 32 + (tid >> 3);
            const int c8  = (tid & 7) * 8;
            const float4* src = (const float4*)(kgh + (size_t)row * D + c8);
            *(bf16x8*)(kbh + (size_t)row * D + c8) = cvt8(src[0], src[1]);
        }
        const int dcol = tid & 63;
        const int jblk = tid >> 6;
#pragma unroll
        for (int c = 0; c < 4; ++c) {
            const int j = slice * 128 + jblk * 32 + c * 8;
            bf16x8 vv;
#pragma unroll
            for (int kk = 0; kk < 8; ++kk)
                vv[kk] = (__bf16)vgh[(size_t)(j + kk) * D + dcol];
            *(bf16x8*)(vth + (size_t)dcol * S + j) = vv;
        }
    }
    __threadfence();
    cg::this_grid().sync();

    const float* qrow = qg + ((size_t)bh * S + q0 + l31) * D + 8 * h2;
    float* att  = ag + (size_t)bh * S * S + (size_t)q0 * S;
    float* orow = og + ((size_t)bh * S + q0) * D;

    // K staging: thread stages 8 bf16 of row (tid>>3), d-chunk tid&7 (16B)
    const int srow  = tid >> 3;
    const int scol  = tid & 7;
    const int sslot = srow * 8 + (scol ^ (srow & 7));
    const unsigned short* ksrc = kb + (size_t)bh * S * D + (size_t)srow * D + scol * 8;
    int kslot[4];
#pragma unroll
    for (int t = 0; t < 4; ++t)
        kslot[t] = l31 * 8 + ((2 * t + h2) ^ (l31 & 7));

    // V staging: thread stages 8 bf16 of V^T row d=tid&63, j-chunk tid>>6 (16B)
    const int vd = tid & 63;
    const int vw = tid >> 6;
    const int vwslot = vd * 4 + (vw ^ ((vd >> 1) & 3));
    const unsigned short* vsrc = vt + (size_t)bh * S * D + (size_t)vd * S + 8 * vw;
    int vslot[2][2];
#pragma unroll
    for (int f = 0; f < 2; ++f)
#pragma unroll
        for (int g = 0; g < 2; ++g) {
            const int d = l31 + 32 * g;
            vslot[f][g] = d * 4 + ((2 * f + h2) ^ ((d >> 1) & 3));
        }

    // Q fragments: row/col q=l31, k = d = 16t+8h2+e (pre-scaled)
    bf16x8 qa[4];
#pragma unroll
    for (int t = 0; t < 4; ++t) {
        const float4* p4 = (const float4*)(qrow + 16 * t);
        qa[t] = cvt8s(p4[0], p4[1], QSCALE);
    }

    // mask bitmap build
    if (tid < 64) {
        const int4* mp = (const int4*)(mg + (size_t)b * S + 32 * tid);
        unsigned int bits = 0;
#pragma unroll
        for (int k = 0; k < 8; ++k) {
            int4 m = mp[k];
            bits |= (unsigned int)(m.x != 0) << (4 * k);
            bits |= (unsigned int)(m.y != 0) << (4 * k + 1);
            bits |= (unsigned int)(m.z != 0) << (4 * k + 2);
            bits |= (unsigned int)(m.w != 0) << (4 * k + 3);
        }
        mlds[tid] = bits;
    }

    // ---- prologue: tile 0 -> buf0; tile 1 -> regs ----
    {
        uint32x4 ku, vu;
        __builtin_memcpy(&ku, ksrc, 16);
        __builtin_memcpy(&vu, vsrc, 16);
        kstage[0][sslot]  = __builtin_bit_cast(bf16x8, ku);
        vstage[0][vwslot] = __builtin_bit_cast(bf16x8, vu);
    }
    uint32x4 k1, v1;
    __builtin_memcpy(&k1, ksrc + (size_t)32 * D, 16);
    __builtin_memcpy(&v1, vsrc + 32, 16);
    __syncthreads();

    // =============== Pass 1: sums + un-normalized PV ===============
    float sums4[4] = {0.f, 0.f, 0.f, 0.f};
    f32x16 oacc[2];
#pragma unroll
    for (int g = 0; g < 2; ++g)
#pragma unroll
        for (int r = 0; r < 16; ++r) oacc[g][r] = 0.f;

    int cur = 0;
    for (int t = 0; t < NT; ++t) {
        const int j0  = t * 32;
        const int nxt = (cur == 2) ? 0 : cur + 1;

        // (a) issue loads for tile t+2 (distance-2 prefetch)
        uint32x4 k2{}, v2{};
        if ((t + 2) < NT) {
            __builtin_memcpy(&k2, ksrc + (size_t)(j0 + 64) * D, 16);
            __builtin_memcpy(&v2, vsrc + (j0 + 64), 16);
        }

        // (b) compute tile t: swapped QK^T, C[row=j][col=q], lane col = q = l31
        f32x16 acc;
#pragma unroll
        for (int r = 0; r < 16; ++r) acc[r] = 0.f;
        __builtin_amdgcn_s_setprio(1);
#pragma unroll
        for (int u = 0; u < 4; ++u)
            acc = __builtin_amdgcn_mfma_f32_32x32x16_bf16(kstage[cur][kslot[u]], qa[u], acc, 0, 0, 0);
        __builtin_amdgcn_s_setprio(0);

        // p_r for j = j0 + (r&3)+8*(r>>2)+4*h2 ; pack quads to bf16 words
        const unsigned int mq = mlds[j0 >> 5] >> (4 * h2);
        unsigned int pk[8];
#pragma unroll
        for (int qd = 0; qd < 4; ++qd) {
            float pv[4];
#pragma unroll
            for (int i = 0; i < 4; ++i) {
                const float e = fexp2(acc[4 * qd + i]);
                pv[i] = ((mq >> (i + 8 * qd)) & 1) ? e : 1.0f;
                sums4[qd] += pv[i];
            }
            pk[2 * qd]     = pkbf(pv[0], pv[1]);
            pk[2 * qd + 1] = pkbf(pv[2], pv[3]);
        }
        // cross-half exchange: PA[0] <- quads {Q0,Q1}, PA[1] <- {Q2,Q3}
        asm volatile("v_permlane32_swap_b32 %0, %1" : "+v"(pk[0]), "+v"(pk[2]));
        asm volatile("v_permlane32_swap_b32 %0, %1" : "+v"(pk[1]), "+v"(pk[3]));
        asm volatile("v_permlane32_swap_b32 %0, %1" : "+v"(pk[4]), "+v"(pk[6]));
        asm volatile("v_permlane32_swap_b32 %0, %1" : "+v"(pk[5]), "+v"(pk[7]));
        uint32x4 u0 = {pk[0], pk[1], pk[2], pk[3]};
        uint32x4 u1 = {pk[4], pk[5], pk[6], pk[7]};
        bf16x8 pa[2];
        pa[0] = __builtin_bit_cast(bf16x8, u0);
        pa[1] = __builtin_bit_cast(bf16x8, u1);

        // PV: O_un[q][d] += P[q][j] * V[j][d]
        __builtin_amdgcn_s_setprio(1);
#pragma unroll
        for (int f = 0; f < 2; ++f)
#pragma unroll
            for (int g = 0; g < 2; ++g)
                oacc[g] = __builtin_amdgcn_mfma_f32_32x32x16_bf16(pa[f], vstage[cur][vslot[f][g]], oacc[g], 0, 0, 0);
        __builtin_amdgcn_s_setprio(0);

        // (c) write tile t+1 staged regs into buf nxt
        if ((t + 1) < NT) {
            kstage[nxt][sslot]  = __builtin_bit_cast(bf16x8, k1);
            vstage[nxt][vwslot] = __builtin_bit_cast(bf16x8, v1);
        }
        __syncthreads();

        // (d) shift prefetch regs
        k1 = k2; v1 = v2;
        cur = nxt;
    }

    // row-sum inverse; lane holds q-row l31 (halves hold partial sums)
    const float ssum = (sums4[0] + sums4[1]) + (sums4[2] + sums4[3]);
    const float inv = 1.0f / (ssum + __shfl_xor(ssum, 32));
    float invq[16];
#pragma unroll
    for (int r = 0; r < 16; ++r)
        invq[r] = __shfl(inv, (r & 3) + 8 * (r >> 2) + 4 * h2);

    // O write, normalized (C layout: row=q, col=d=l31+32g)
#pragma unroll
    for (int g = 0; g < 2; ++g)
#pragma unroll
        for (int r = 0; r < 16; ++r) {
            const int qr = (r & 3) + 8 * (r >> 2) + 4 * h2;
            __builtin_nontemporal_store(oacc[g][r] * invq[r],
                                        &orow[(size_t)qr * D + 32 * g + l31]);
        }

    // =============== Pass 2: attention write (lean, double-buffered) ===============
    {
        uint32x4 ku;
        __builtin_memcpy(&ku, ksrc, 16);
        kstage[0][sslot] = __builtin_bit_cast(bf16x8, ku);
    }
    __syncthreads();

    cur = 0;
    for (int j0 = 0; j0 < S; j0 += 32) {
        const bool more = (j0 + 32) < S;
        uint32x4 kn{};
        if (more)
            __builtin_memcpy(&kn, ksrc + (size_t)(j0 + 32) * D, 16);
        const bool mf = (mlds[j0 >> 5] >> l31) & 1;

        // normal QK^T: C[row=q][col=j], lane col = j = l31 -> coalesced stores
        f32x16 acc;
#pragma unroll
        for (int r = 0; r < 16; ++r) acc[r] = 0.f;
        __builtin_amdgcn_s_setprio(1);
#pragma unroll
        for (int u = 0; u < 4; ++u)
            acc = __builtin_amdgcn_mfma_f32_32x32x16_bf16(qa[u], kstage[cur][kslot[u]], acc, 0, 0, 0);
        __builtin_amdgcn_s_setprio(0);

#pragma unroll
        for (int r = 0; r < 16; ++r) {
            float p = mf ? fexp2(acc[r]) : 1.0f;
            p *= invq[r];
            const int qr = (r & 3) + 8 * (r >> 2) + 4 * h2;
            __builtin_nontemporal_store(p, &att[(size_t)qr * S + j0 + l31]);
        }
        if (more) kstage[cur ^ 1][sslot] = __builtin_bit_cast(bf16x8, kn);
        __syncthreads();
        cur ^= 1;
    }
}

// ================= Fallback: round-7 kernel (verified, 289.6 us) =================
__global__ void __launch_bounds__(256, 4)
attn_fused(const float* __restrict__ qg, const float* __restrict__ kg,
           const float* __restrict__ vg, const int* __restrict__ mg,
           float* __restrict__ og, float* __restrict__ ag)
{
    __shared__ bf16x8 kstage[3][256];
    __shared__ bf16x8 vstage[3][256];
    __shared__ unsigned int mlds[64];

    const int tid  = threadIdx.x;
    const int lane = tid & 63;
    const int w    = tid >> 6;
    const int l31  = lane & 31;
    const int h2   = lane >> 5;

    const int wid = (blockIdx.x & 7) * 128 + (blockIdx.x >> 3);
    const int bh  = wid >> 4;
    const int q0  = ((wid & 15) * 4 + w) * 32;
    const int b   = bh >> 4;

    const float* qrow = qg + ((size_t)bh * S + q0 + l31) * D + 8 * h2;
    const float* vb_  = vg + (size_t)bh * S * D;
    float* att  = ag + (size_t)bh * S * S + (size_t)q0 * S;
    float* orow = og + ((size_t)bh * S + q0) * D;

    const int srow  = tid >> 3;
    const int scol  = tid & 7;
    const int sslot = srow * 8 + (scol ^ (srow & 7));
    const float* ksrc = kg + (size_t)bh * S * D + (size_t)srow * D + scol * 8;
    int kslot[4];
#pragma unroll
    for (int t = 0; t < 4; ++t)
        kslot[t] = l31 * 8 + ((2 * t + h2) ^ (l31 & 7));

    const int vd = tid & 63;
    const int vw = tid >> 6;
    const int vwslot = vd * 4 + (vw ^ ((vd >> 1) & 3));
    const float* vsrc = vb_ + vd;
    int vslot[2][2];
#pragma unroll
    for (int f = 0; f < 2; ++f)
#pragma unroll
        for (int g = 0; g < 2; ++g) {
            const int d = l31 + 32 * g;
            vslot[f][g] = d * 4 + ((2 * f + h2) ^ ((d >> 1) & 3));
        }

    bf16x8 qa[4];
#pragma unroll
    for (int t = 0; t < 4; ++t) {
        const float4* p4 = (const float4*)(qrow + 16 * t);
        qa[t] = cvt8s(p4[0], p4[1], QSCALE);
    }

    if (tid < 64) {
        const int4* mp = (const int4*)(mg + (size_t)b * S + 32 * tid);
        unsigned int bits = 0;
#pragma unroll
        for (int k = 0; k < 8; ++k) {
            int4 m = mp[k];
            bits |= (unsigned int)(m.x != 0) << (4 * k);
            bits |= (unsigned int)(m.y != 0) << (4 * k + 1);
            bits |= (unsigned int)(m.z != 0) << (4 * k + 2);
            bits |= (unsigned int)(m.w != 0) << (4 * k + 3);
        }
        mlds[tid] = bits;
    }

    {
        const float4* p4 = (const float4*)ksrc;
        kstage[0][sslot] = cvt8(p4[0], p4[1]);
        bf16x8 vv;
#pragma unroll
        for (int k = 0; k < 8; ++k)
            vv[k] = (__bf16)vsrc[(size_t)(8 * vw + k) * D];
        vstage[0][vwslot] = vv;
    }
    float4 k1a, k1b;
    float  v1[8];
    {
        const float4* p4 = (const float4*)(ksrc + (size_t)32 * D);
        k1a = p4[0]; k1b = p4[1];
#pragma unroll
        for (int k = 0; k < 8; ++k)
            v1[k] = vsrc[(size_t)(32 + 8 * vw + k) * D];
    }
    __syncthreads();

    float sums4[4] = {0.f, 0.f, 0.f, 0.f};
    f32x16 oacc[2];
#pragma unroll
    for (int g = 0; g < 2; ++g)
#pragma unroll
        for (int r = 0; r < 16; ++r) oacc[g][r] = 0.f;

    int cur = 0;
    for (int t = 0; t < NT; ++t) {
        const int j0  = t * 32;
        const int nxt = (cur == 2) ? 0 : cur + 1;

        float4 k2a{}, k2b{};
        float  v2[8];
        const bool have2 = (t + 2) < NT;
        if (have2) {
            const float4* p4 = (const float4*)(ksrc + (size_t)(j0 + 64) * D);
            k2a = p4[0]; k2b = p4[1];
#pragma unroll
            for (int k = 0; k < 8; ++k)
                v2[k] = vsrc[(size_t)(j0 + 64 + 8 * vw + k) * D];
        }

        f32x16 acc;
#pragma unroll
        for (int r = 0; r < 16; ++r) acc[r] = 0.f;
        __builtin_amdgcn_s_setprio(1);
#pragma unroll
        for (int u = 0; u < 4; ++u)
            acc = __builtin_amdgcn_mfma_f32_32x32x16_bf16(kstage[cur][kslot[u]], qa[u], acc, 0, 0, 0);
        __builtin_amdgcn_s_setprio(0);

        const unsigned int mq = mlds[j0 >> 5] >> (4 * h2);
        unsigned int pk[8];
#pragma unroll
        for (int qd = 0; qd < 4; ++qd) {
            float pv[4];
#pragma unroll
            for (int i = 0; i < 4; ++i) {
                const float e = fexp2(acc[4 * qd + i]);
                pv[i] = ((mq >> (i + 8 * qd)) & 1) ? e : 1.0f;
                sums4[qd] += pv[i];
            }
            pk[2 * qd]     = pkbf(pv[0], pv[1]);
            pk[2 * qd + 1] = pkbf(pv[2], pv[3]);
        }
        asm volatile("v_permlane32_swap_b32 %0, %1" : "+v"(pk[0]), "+v"(pk[2]));
        asm volatile("v_permlane32_swap_b32 %0, %1" : "+v"(pk[1]), "+v"(pk[3]));
        asm volatile("v_permlane32_swap_b32 %0, %1" : "+v"(pk[4]), "+v"(pk[6]));
        asm volatile("v_permlane32_swap_b32 %0, %1" : "+v"(pk[5]), "+v"(pk[7]));
        uint32x4 u0 = {pk[0], pk[1], pk[2], pk[3]};
        uint32x4 u1 = {pk[4], pk[5], pk[6], pk[7]};
        bf16x8 pa[2];
        pa[0] = __builtin_bit_cast(bf16x8, u0);
        pa[1] = __builtin_bit_cast(bf16x8, u1);

        __builtin_amdgcn_s_setprio(1);
#pragma unroll
        for (int f = 0; f < 2; ++f)
#pragma unroll
            for (int g = 0; g < 2; ++g)
                oacc[g] = __builtin_amdgcn_mfma_f32_32x32x16_bf16(pa[f], vstage[cur][vslot[f][g]], oacc[g], 0, 0, 0);
        __builtin_amdgcn_s_setprio(0);

        if ((t + 1) < NT) {
            kstage[nxt][sslot] = cvt8(k1a, k1b);
            bf16x8 vv;
#pragma unroll
            for (int k = 0; k < 8; ++k) vv[k] = (__bf16)v1[k];
            vstage[nxt][vwslot] = vv;
        }
        __syncthreads();

        k1a = k2a; k1b = k2b;
#pragma unroll
        for (int k = 0; k < 8; ++k) v1[k] = v2[k];
        cur = nxt;
    }

    const float ssum = (sums4[0] + sums4[1]) + (sums4[2] + sums4[3]);
    const float inv = 1.0f / (ssum + __shfl_xor(ssum, 32));
    float invq[16];
#pragma unroll
    for (int r = 0; r < 16; ++r)
        invq[r] = __shfl(inv, (r & 3) + 8 * (r >> 2) + 4 * h2);

#pragma unroll
    for (int g = 0; g < 2; ++g)
#pragma unroll
        for (int r = 0; r < 16; ++r) {
            const int qr = (r & 3) + 8 * (r >> 2) + 4 * h2;
            __builtin_nontemporal_store(oacc[g][r] * invq[r],
                                        &orow[(size_t)qr * D + 32 * g + l31]);
        }

    {
        const float4* p4 = (const float4*)ksrc;
        kstage[0][sslot] = cvt8(p4[0], p4[1]);
    }
    __syncthreads();

    cur = 0;
    for (int j0 = 0; j0 < S; j0 += 32) {
        const bool more = (j0 + 32) < S;
        float4 kna{}, knb{};
        if (more) {
            const float4* p4 = (const float4*)(ksrc + (size_t)(j0 + 32) * D);
            kna = p4[0]; knb = p4[1];
        }
        const bool mf = (mlds[j0 >> 5] >> l31) & 1;

        f32x16 acc;
#pragma unroll
        for (int r = 0; r < 16; ++r) acc[r] = 0.f;
        __builtin_amdgcn_s_setprio(1);
#pragma unroll
        for (int u = 0; u < 4; ++u)
            acc = __builtin_amdgcn_mfma_f32_32x32x16_bf16(qa[u], kstage[cur][kslot[u]], acc, 0, 0, 0);
        __builtin_amdgcn_s_setprio(0);

#pragma unroll
        for (int r = 0; r < 16; ++r) {
            float p = mf ? fexp2(acc[r]) : 1.0f;
            p *= invq[r];
            const int qr = (r & 3) + 8 * (r >> 2) + 4 * h2;
            __builtin_nontemporal_store(p, &att[(size_t)qr * S + j0 + l31]);
        }
        if (more) kstage[cur ^ 1][sslot] = cvt8(kna, knb);
        __syncthreads();
        cur ^= 1;
    }
}

extern "C" void kernel_launch(void* const* d_in, const int* in_sizes, int n_in,
                              void* d_out, int out_size, void* d_ws, size_t ws_size,
                              hipStream_t stream) {
    const float* q    = (const float*)d_in[0];
    const float* k    = (const float*)d_in[1];
    const float* v    = (const float*)d_in[2];
    const int*   mask = (const int*)d_in[3];
    float* out = (float*)d_out;                       // [B,H,S,D] output first
    float* att = out + (size_t)64 * S * D;            // then [B,H,S,S] attention

    const size_t kv_elems = (size_t)64 * S * D;
    const size_t kv_bytes = kv_elems * sizeof(unsigned short);   // 16.78 MB each
    bool done = false;
    if (ws_size >= 2 * kv_bytes) {
        unsigned short* kb = (unsigned short*)d_ws;
        unsigned short* vt = kb + kv_elems;
        void* args[] = {(void*)&q, (void*)&k, (void*)&v, (void*)&mask,
                        (void*)&out, (void*)&att, (void*)&kb, (void*)&vt};
        hipError_t e = hipLaunchCooperativeKernel((void*)attn_coop,
                                                  dim3(1024), dim3(256),
                                                  args, 0, stream);
        done = (e == hipSuccess);
    }
    if (!done) {
        hipLaunchKernelGGL(attn_fused, dim3(1024), dim3(256), 0, stream,
                           q, k, v, mask, out, att);
    }
}

// Round 9
// 294.650 us; speedup vs baseline: 1.8404x; 1.8404x over previous
//
#include <hip/hip_runtime.h>
#include <hip/hip_bf16.h>

namespace {

constexpr int S = 2048;
constexpr int D = 64;
constexpr int NT = S / 32;   // 64 j-tiles
// 64^-0.5 * log2(e) folded into the Q cast: exp(q.k/8) == exp2((q*QSCALE).k)
constexpr float QSCALE = 0.125f * 1.4426950408889634f;

typedef __bf16 bf16x8 __attribute__((ext_vector_type(8)));
typedef float f32x16 __attribute__((ext_vector_type(16)));
typedef unsigned int uint32x4 __attribute__((ext_vector_type(4)));

#if __has_builtin(__builtin_amdgcn_exp2f)
__device__ __forceinline__ float fexp2(float x) { return __builtin_amdgcn_exp2f(x); }
#else
__device__ __forceinline__ float fexp2(float x) { return exp2f(x); }
#endif

__device__ __forceinline__ bf16x8 cvt8s(float4 a, float4 b, float s) {
    bf16x8 f;
    f[0] = (__bf16)(a.x * s); f[1] = (__bf16)(a.y * s);
    f[2] = (__bf16)(a.z * s); f[3] = (__bf16)(a.w * s);
    f[4] = (__bf16)(b.x * s); f[5] = (__bf16)(b.y * s);
    f[6] = (__bf16)(b.z * s); f[7] = (__bf16)(b.w * s);
    return f;
}
__device__ __forceinline__ bf16x8 cvt8(float4 a, float4 b) {
    bf16x8 f;
    f[0] = (__bf16)a.x; f[1] = (__bf16)a.y;
    f[2] = (__bf16)a.z; f[3] = (__bf16)a.w;
    f[4] = (__bf16)b.x; f[5] = (__bf16)b.y;
    f[6] = (__bf16)b.z; f[7] = (__bf16)b.w;
    return f;
}
__device__ __forceinline__ unsigned int pkbf(float lo, float hi) {
    unsigned int a = (unsigned int)__builtin_bit_cast(unsigned short, (__bf16)lo);
    unsigned int b = (unsigned int)__builtin_bit_cast(unsigned short, (__bf16)hi);
    return a | (b << 16);
}

} // namespace

// Block = 4 waves; each wave owns SIXTY-FOUR q-rows (two 32-row sets sharing
// one K/V stream) of one (b,h). 8 blocks per head (was 16) -> K/V HBM
// re-fetch demand halves in both passes.
// Pass 1 (swapped QK^T, triple-buffered LDS, distance-2 prefetch):
//   per set: l = sum_j exp(s); O_un += exp(s)*V via in-register P build
//   (pack + v_permlane32_swap_b32); O = O_un / l at the end.
// Pass 2 (normal QK^T, double-buffered): att = exp(s)/l, NT coalesced stores.
__global__ void __launch_bounds__(256, 2)
attn_fused(const float* __restrict__ qg, const float* __restrict__ kg,
           const float* __restrict__ vg, const int* __restrict__ mg,
           float* __restrict__ og, float* __restrict__ ag)
{
    __shared__ bf16x8 kstage[3][256];        // K tile [j=32][8 d-chunks], XOR slot
    __shared__ bf16x8 vstage[3][256];        // V tile transposed [d=64][4 j-chunks]
    __shared__ unsigned int mlds[64];        // mask bitmap: bit j&31 of word j>>5

    const int tid  = threadIdx.x;
    const int lane = tid & 63;
    const int w    = tid >> 6;
    const int l31  = lane & 31;
    const int h2   = lane >> 5;

    // XCD-aware remap over 512 blocks: XCD x gets wid in [x*64, x*64+63]
    // = heads x*8..x*8+7 (K/V L2-resident per XCD).
    const int wid = (blockIdx.x & 7) * 64 + (blockIdx.x >> 3);
    const int bh  = wid >> 3;                  // head 0..63
    const int q0  = ((wid & 7) * 4 + w) * 64;  // 64 q-rows per wave
    const int b   = bh >> 4;

    const float* vb_  = vg + (size_t)bh * S * D;
    float* att  = ag + (size_t)bh * S * S + (size_t)q0 * S;
    float* orow = og + ((size_t)bh * S + q0) * D;

    // K staging: thread stages 8 f32 of row (tid>>3), d-chunk tid&7
    const int srow  = tid >> 3;
    const int scol  = tid & 7;
    const int sslot = srow * 8 + (scol ^ (srow & 7));
    const float* ksrc = kg + (size_t)bh * S * D + (size_t)srow * D + scol * 8;
    int kslot[4];
#pragma unroll
    for (int t = 0; t < 4; ++t)
        kslot[t] = l31 * 8 + ((2 * t + h2) ^ (l31 & 7));

    // V staging (transposed): thread owns column d=tid&63, j-chunk vw=tid>>6
    const int vd = tid & 63;
    const int vw = tid >> 6;
    const int vwslot = vd * 4 + (vw ^ ((vd >> 1) & 3));
    const float* vsrc = vb_ + vd;
    int vslot[2][2];
#pragma unroll
    for (int f = 0; f < 2; ++f)
#pragma unroll
        for (int g = 0; g < 2; ++g) {
            const int d = l31 + 32 * g;
            vslot[f][g] = d * 4 + ((2 * f + h2) ^ ((d >> 1) & 3));
        }

    // Q fragments, two 32-row sets: set s covers rows q0+32s .. q0+32s+31
    bf16x8 qa[2][4];
#pragma unroll
    for (int s = 0; s < 2; ++s) {
        const float* qrow = qg + ((size_t)bh * S + q0 + 32 * s + l31) * D + 8 * h2;
#pragma unroll
        for (int t = 0; t < 4; ++t) {
            const float4* p4 = (const float4*)(qrow + 16 * t);
            qa[s][t] = cvt8s(p4[0], p4[1], QSCALE);
        }
    }

    // mask bitmap build
    if (tid < 64) {
        const int4* mp = (const int4*)(mg + (size_t)b * S + 32 * tid);
        unsigned int bits = 0;
#pragma unroll
        for (int k = 0; k < 8; ++k) {
            int4 m = mp[k];
            bits |= (unsigned int)(m.x != 0) << (4 * k);
            bits |= (unsigned int)(m.y != 0) << (4 * k + 1);
            bits |= (unsigned int)(m.z != 0) << (4 * k + 2);
            bits |= (unsigned int)(m.w != 0) << (4 * k + 3);
        }
        mlds[tid] = bits;
    }

    // ---- prologue: tile 0 -> buf0; tile 1 -> regs ----
    {
        const float4* p4 = (const float4*)ksrc;
        kstage[0][sslot] = cvt8(p4[0], p4[1]);
        bf16x8 vv;
#pragma unroll
        for (int k = 0; k < 8; ++k)
            vv[k] = (__bf16)vsrc[(size_t)(8 * vw + k) * D];
        vstage[0][vwslot] = vv;
    }
    float4 k1a, k1b;
    float  v1[8];
    {
        const float4* p4 = (const float4*)(ksrc + (size_t)32 * D);
        k1a = p4[0]; k1b = p4[1];
#pragma unroll
        for (int k = 0; k < 8; ++k)
            v1[k] = vsrc[(size_t)(32 + 8 * vw + k) * D];
    }
    __syncthreads();

    // =============== Pass 1: sums + un-normalized PV (both sets) ===============
    float sums4[2][4] = {{0.f, 0.f, 0.f, 0.f}, {0.f, 0.f, 0.f, 0.f}};
    f32x16 oacc[2][2];
#pragma unroll
    for (int s = 0; s < 2; ++s)
#pragma unroll
        for (int g = 0; g < 2; ++g)
#pragma unroll
            for (int r = 0; r < 16; ++r) oacc[s][g][r] = 0.f;

    int cur = 0;
    for (int t = 0; t < NT; ++t) {
        const int j0  = t * 32;
        const int nxt = (cur == 2) ? 0 : cur + 1;

        // (a) issue loads for tile t+2 (distance-2 prefetch)
        float4 k2a{}, k2b{};
        float  v2[8];
        if ((t + 2) < NT) {
            const float4* p4 = (const float4*)(ksrc + (size_t)(j0 + 64) * D);
            k2a = p4[0]; k2b = p4[1];
#pragma unroll
            for (int k = 0; k < 8; ++k)
                v2[k] = vsrc[(size_t)(j0 + 64 + 8 * vw + k) * D];
        }

        // (b) hoist K/V fragments once; reused by both q-sets
        bf16x8 kf[4];
#pragma unroll
        for (int u = 0; u < 4; ++u) kf[u] = kstage[cur][kslot[u]];
        bf16x8 vf[2][2];
#pragma unroll
        for (int f = 0; f < 2; ++f)
#pragma unroll
            for (int g = 0; g < 2; ++g) vf[f][g] = vstage[cur][vslot[f][g]];

        const unsigned int mq = mlds[j0 >> 5] >> (4 * h2);

#pragma unroll
        for (int s = 0; s < 2; ++s) {
            // swapped QK^T: C[row=j][col=q], lane col = q = l31
            f32x16 acc;
#pragma unroll
            for (int r = 0; r < 16; ++r) acc[r] = 0.f;
            __builtin_amdgcn_s_setprio(1);
#pragma unroll
            for (int u = 0; u < 4; ++u)
                acc = __builtin_amdgcn_mfma_f32_32x32x16_bf16(kf[u], qa[s][u], acc, 0, 0, 0);
            __builtin_amdgcn_s_setprio(0);

            // p_r for j = j0 + (r&3)+8*(r>>2)+4*h2 ; pack quads to bf16 words
            unsigned int pk[8];
#pragma unroll
            for (int qd = 0; qd < 4; ++qd) {
                float pv[4];
#pragma unroll
                for (int i = 0; i < 4; ++i) {
                    const float e = fexp2(acc[4 * qd + i]);
                    pv[i] = ((mq >> (i + 8 * qd)) & 1) ? e : 1.0f;
                    sums4[s][qd] += pv[i];
                }
                pk[2 * qd]     = pkbf(pv[0], pv[1]);
                pk[2 * qd + 1] = pkbf(pv[2], pv[3]);
            }
            // cross-half exchange: PA[0] <- quads {Q0,Q1}, PA[1] <- {Q2,Q3}
            asm volatile("v_permlane32_swap_b32 %0, %1" : "+v"(pk[0]), "+v"(pk[2]));
            asm volatile("v_permlane32_swap_b32 %0, %1" : "+v"(pk[1]), "+v"(pk[3]));
            asm volatile("v_permlane32_swap_b32 %0, %1" : "+v"(pk[4]), "+v"(pk[6]));
            asm volatile("v_permlane32_swap_b32 %0, %1" : "+v"(pk[5]), "+v"(pk[7]));
            uint32x4 u0 = {pk[0], pk[1], pk[2], pk[3]};
            uint32x4 u1 = {pk[4], pk[5], pk[6], pk[7]};
            bf16x8 pa[2];
            pa[0] = __builtin_bit_cast(bf16x8, u0);
            pa[1] = __builtin_bit_cast(bf16x8, u1);

            // PV: O_un[q][d] += P[q][j] * V[j][d]
            __builtin_amdgcn_s_setprio(1);
#pragma unroll
            for (int f = 0; f < 2; ++f)
#pragma unroll
                for (int g = 0; g < 2; ++g)
                    oacc[s][g] = __builtin_amdgcn_mfma_f32_32x32x16_bf16(pa[f], vf[f][g], oacc[s][g], 0, 0, 0);
            __builtin_amdgcn_s_setprio(0);
        }

        // (c) write tile t+1 staged regs into buf nxt
        if ((t + 1) < NT) {
            kstage[nxt][sslot] = cvt8(k1a, k1b);
            bf16x8 vv;
#pragma unroll
            for (int k = 0; k < 8; ++k) vv[k] = (__bf16)v1[k];
            vstage[nxt][vwslot] = vv;
        }
        __syncthreads();

        // (d) shift prefetch regs
        k1a = k2a; k1b = k2b;
#pragma unroll
        for (int k = 0; k < 8; ++k) v1[k] = v2[k];
        cur = nxt;
    }

    // per-set row-sum inverse + O write (frees oacc before pass 2)
    float invq[2][16];
#pragma unroll
    for (int s = 0; s < 2; ++s) {
        const float ssum = (sums4[s][0] + sums4[s][1]) + (sums4[s][2] + sums4[s][3]);
        const float inv = 1.0f / (ssum + __shfl_xor(ssum, 32));
#pragma unroll
        for (int r = 0; r < 16; ++r)
            invq[s][r] = __shfl(inv, (r & 3) + 8 * (r >> 2) + 4 * h2);
#pragma unroll
        for (int g = 0; g < 2; ++g)
#pragma unroll
            for (int r = 0; r < 16; ++r) {
                const int qr = 32 * s + (r & 3) + 8 * (r >> 2) + 4 * h2;
                __builtin_nontemporal_store(oacc[s][g][r] * invq[s][r],
                                            &orow[(size_t)qr * D + 32 * g + l31]);
            }
    }

    // =============== Pass 2: attention write (lean, double-buffered) ===============
    {
        const float4* p4 = (const float4*)ksrc;
        kstage[0][sslot] = cvt8(p4[0], p4[1]);
    }
    __syncthreads();

    cur = 0;
    for (int j0 = 0; j0 < S; j0 += 32) {
        const bool more = (j0 + 32) < S;
        float4 kna{}, knb{};
        if (more) {
            const float4* p4 = (const float4*)(ksrc + (size_t)(j0 + 32) * D);
            kna = p4[0]; knb = p4[1];
        }
        const bool mf = (mlds[j0 >> 5] >> l31) & 1;

        bf16x8 kf[4];
#pragma unroll
        for (int u = 0; u < 4; ++u) kf[u] = kstage[cur][kslot[u]];

#pragma unroll
        for (int s = 0; s < 2; ++s) {
            // normal QK^T: C[row=q][col=j], lane col = j = l31 -> coalesced
            f32x16 acc;
#pragma unroll
            for (int r = 0; r < 16; ++r) acc[r] = 0.f;
            __builtin_amdgcn_s_setprio(1);
#pragma unroll
            for (int u = 0; u < 4; ++u)
                acc = __builtin_amdgcn_mfma_f32_32x32x16_bf16(qa[s][u], kf[u], acc, 0, 0, 0);
            __builtin_amdgcn_s_setprio(0);

#pragma unroll
            for (int r = 0; r < 16; ++r) {
                float p = mf ? fexp2(acc[r]) : 1.0f;
                p *= invq[s][r];
                const int qr = 32 * s + (r & 3) + 8 * (r >> 2) + 4 * h2;
                __builtin_nontemporal_store(p, &att[(size_t)qr * S + j0 + l31]);
            }
        }
        if (more) kstage[cur ^ 1][sslot] = cvt8(kna, knb);
        __syncthreads();
        cur ^= 1;
    }
}

extern "C" void kernel_launch(void* const* d_in, const int* in_sizes, int n_in,
                              void* d_out, int out_size, void* d_ws, size_t ws_size,
                              hipStream_t stream) {
    const float* q    = (const float*)d_in[0];
    const float* k    = (const float*)d_in[1];
    const float* v    = (const float*)d_in[2];
    const int*   mask = (const int*)d_in[3];
    float* out = (float*)d_out;                       // [B,H,S,D] output first
    float* att = out + (size_t)64 * S * D;            // then [B,H,S,S] attention
    hipLaunchKernelGGL(attn_fused, dim3(512), dim3(256), 0, stream,
                       q, k, v, mask, out, att);
}

// Round 12
// 288.477 us; speedup vs baseline: 1.8798x; 1.0214x over previous
//
#include <hip/hip_runtime.h>
#include <hip/hip_bf16.h>

namespace {

constexpr int S = 2048;
constexpr int D = 64;
constexpr int NT = S / 32;   // 64 j-tiles
// 64^-0.5 * log2(e) folded into the Q cast: exp(q.k/8) == exp2((q*QSCALE).k)
constexpr float QSCALE = 0.125f * 1.4426950408889634f;

typedef __bf16 bf16x8 __attribute__((ext_vector_type(8)));
typedef float f32x16 __attribute__((ext_vector_type(16)));
typedef unsigned int uint32x4 __attribute__((ext_vector_type(4)));

#if __has_builtin(__builtin_amdgcn_exp2f)
__device__ __forceinline__ float fexp2(float x) { return __builtin_amdgcn_exp2f(x); }
#else
__device__ __forceinline__ float fexp2(float x) { return exp2f(x); }
#endif

__device__ __forceinline__ bf16x8 cvt8s(float4 a, float4 b, float s) {
    bf16x8 f;
    f[0] = (__bf16)(a.x * s); f[1] = (__bf16)(a.y * s);
    f[2] = (__bf16)(a.z * s); f[3] = (__bf16)(a.w * s);
    f[4] = (__bf16)(b.x * s); f[5] = (__bf16)(b.y * s);
    f[6] = (__bf16)(b.z * s); f[7] = (__bf16)(b.w * s);
    return f;
}
__device__ __forceinline__ bf16x8 cvt8(float4 a, float4 b) {
    bf16x8 f;
    f[0] = (__bf16)a.x; f[1] = (__bf16)a.y;
    f[2] = (__bf16)a.z; f[3] = (__bf16)a.w;
    f[4] = (__bf16)b.x; f[5] = (__bf16)b.y;
    f[6] = (__bf16)b.z; f[7] = (__bf16)b.w;
    return f;
}
__device__ __forceinline__ unsigned int pkbf(float lo, float hi) {
    unsigned int a = (unsigned int)__builtin_bit_cast(unsigned short, (__bf16)lo);
    unsigned int b = (unsigned int)__builtin_bit_cast(unsigned short, (__bf16)hi);
    return a | (b << 16);
}

} // namespace

// Round-7 champion, verbatim (passed: 289.6 us, absmax 0.00390625).
// Block = 4 waves, each wave owns 32 q-rows of one (b,h).
// Pass 1 (swapped QK^T, triple-buffered LDS, prefetch distance 2):
//   l = sum_j exp(s); O_un += exp(s)*V via in-register P build
//   (pack + v_permlane32_swap_b32); O = O_un / l at the end.
// Pass 2 (normal QK^T, double-buffered): att = exp(s)/l, NT coalesced stores.
__global__ void __launch_bounds__(256, 4)
attn_fused(const float* __restrict__ qg, const float* __restrict__ kg,
           const float* __restrict__ vg, const int* __restrict__ mg,
           float* __restrict__ og, float* __restrict__ ag)
{
    __shared__ bf16x8 kstage[3][256];        // K tile [j=32][8 d-chunks], XOR slot
    __shared__ bf16x8 vstage[3][256];        // V tile transposed [d=64][4 j-chunks]
    __shared__ unsigned int mlds[64];        // mask bitmap: bit j&31 of word j>>5

    const int tid  = threadIdx.x;
    const int lane = tid & 63;
    const int w    = tid >> 6;
    const int l31  = lane & 31;
    const int h2   = lane >> 5;

    // XCD-aware remap: 8 contiguous heads per XCD -> K/V L2-resident
    const int wid = (blockIdx.x & 7) * 128 + (blockIdx.x >> 3);
    const int bh  = wid >> 4;
    const int q0  = ((wid & 15) * 4 + w) * 32;
    const int b   = bh >> 4;

    const float* qrow = qg + ((size_t)bh * S + q0 + l31) * D + 8 * h2;
    const float* vb_  = vg + (size_t)bh * S * D;
    float* att  = ag + (size_t)bh * S * S + (size_t)q0 * S;
    float* orow = og + ((size_t)bh * S + q0) * D;

    // K staging: thread stages 8 f32 of row (tid>>3), d-chunk tid&7
    const int srow  = tid >> 3;
    const int scol  = tid & 7;
    const int sslot = srow * 8 + (scol ^ (srow & 7));
    const float* ksrc = kg + (size_t)bh * S * D + (size_t)srow * D + scol * 8;
    int kslot[4];
#pragma unroll
    for (int t = 0; t < 4; ++t)
        kslot[t] = l31 * 8 + ((2 * t + h2) ^ (l31 & 7));

    // V staging (transposed): thread owns column d=tid&63, j-chunk vw=tid>>6
    const int vd = tid & 63;
    const int vw = tid >> 6;
    const int vwslot = vd * 4 + (vw ^ ((vd >> 1) & 3));
    const float* vsrc = vb_ + vd;
    int vslot[2][2];
#pragma unroll
    for (int f = 0; f < 2; ++f)
#pragma unroll
        for (int g = 0; g < 2; ++g) {
            const int d = l31 + 32 * g;
            vslot[f][g] = d * 4 + ((2 * f + h2) ^ ((d >> 1) & 3));
        }

    // Q fragments: row/col q=l31, k = d = 16t+8h2+e (pre-scaled)
    bf16x8 qa[4];
#pragma unroll
    for (int t = 0; t < 4; ++t) {
        const float4* p4 = (const float4*)(qrow + 16 * t);
        qa[t] = cvt8s(p4[0], p4[1], QSCALE);
    }

    // mask bitmap build
    if (tid < 64) {
        const int4* mp = (const int4*)(mg + (size_t)b * S + 32 * tid);
        unsigned int bits = 0;
#pragma unroll
        for (int k = 0; k < 8; ++k) {
            int4 m = mp[k];
            bits |= (unsigned int)(m.x != 0) << (4 * k);
            bits |= (unsigned int)(m.y != 0) << (4 * k + 1);
            bits |= (unsigned int)(m.z != 0) << (4 * k + 2);
            bits |= (unsigned int)(m.w != 0) << (4 * k + 3);
        }
        mlds[tid] = bits;
    }

    // ---- prologue: tile 0 -> buf0; tile 1 -> regs ----
    {
        const float4* p4 = (const float4*)ksrc;
        kstage[0][sslot] = cvt8(p4[0], p4[1]);
        bf16x8 vv;
#pragma unroll
        for (int k = 0; k < 8; ++k)
            vv[k] = (__bf16)vsrc[(size_t)(8 * vw + k) * D];
        vstage[0][vwslot] = vv;
    }
    float4 k1a, k1b;
    float  v1[8];
    {
        const float4* p4 = (const float4*)(ksrc + (size_t)32 * D);
        k1a = p4[0]; k1b = p4[1];
#pragma unroll
        for (int k = 0; k < 8; ++k)
            v1[k] = vsrc[(size_t)(32 + 8 * vw + k) * D];
    }
    __syncthreads();

    // =============== Pass 1: sums + un-normalized PV ===============
    float sums4[4] = {0.f, 0.f, 0.f, 0.f};
    f32x16 oacc[2];
#pragma unroll
    for (int g = 0; g < 2; ++g)
#pragma unroll
        for (int r = 0; r < 16; ++r) oacc[g][r] = 0.f;

    int cur = 0;
    for (int t = 0; t < NT; ++t) {
        const int j0  = t * 32;
        const int nxt = (cur == 2) ? 0 : cur + 1;

        // (a) issue loads for tile t+2 (distance-2 prefetch)
        float4 k2a{}, k2b{};
        float  v2[8];
        if ((t + 2) < NT) {
            const float4* p4 = (const float4*)(ksrc + (size_t)(j0 + 64) * D);
            k2a = p4[0]; k2b = p4[1];
#pragma unroll
            for (int k = 0; k < 8; ++k)
                v2[k] = vsrc[(size_t)(j0 + 64 + 8 * vw + k) * D];
        }

        // (b) compute tile t: swapped QK^T, C[row=j][col=q], lane col = q = l31
        f32x16 acc;
#pragma unroll
        for (int r = 0; r < 16; ++r) acc[r] = 0.f;
        __builtin_amdgcn_s_setprio(1);
#pragma unroll
        for (int u = 0; u < 4; ++u)
            acc = __builtin_amdgcn_mfma_f32_32x32x16_bf16(kstage[cur][kslot[u]], qa[u], acc, 0, 0, 0);
        __builtin_amdgcn_s_setprio(0);

        // p_r for j = j0 + (r&3)+8*(r>>2)+4*h2 ; pack quads to bf16 words
        const unsigned int mq = mlds[j0 >> 5] >> (4 * h2);
        unsigned int pk[8];
#pragma unroll
        for (int qd = 0; qd < 4; ++qd) {
            float pv[4];
#pragma unroll
            for (int i = 0; i < 4; ++i) {
                const float e = fexp2(acc[4 * qd + i]);
                pv[i] = ((mq >> (i + 8 * qd)) & 1) ? e : 1.0f;
                sums4[qd] += pv[i];
            }
            pk[2 * qd]     = pkbf(pv[0], pv[1]);
            pk[2 * qd + 1] = pkbf(pv[2], pv[3]);
        }
        // cross-half exchange: PA[0] <- quads {Q0,Q1}, PA[1] <- {Q2,Q3}
        asm volatile("v_permlane32_swap_b32 %0, %1" : "+v"(pk[0]), "+v"(pk[2]));
        asm volatile("v_permlane32_swap_b32 %0, %1" : "+v"(pk[1]), "+v"(pk[3]));
        asm volatile("v_permlane32_swap_b32 %0, %1" : "+v"(pk[4]), "+v"(pk[6]));
        asm volatile("v_permlane32_swap_b32 %0, %1" : "+v"(pk[5]), "+v"(pk[7]));
        uint32x4 u0 = {pk[0], pk[1], pk[2], pk[3]};
        uint32x4 u1 = {pk[4], pk[5], pk[6], pk[7]};
        bf16x8 pa[2];
        pa[0] = __builtin_bit_cast(bf16x8, u0);
        pa[1] = __builtin_bit_cast(bf16x8, u1);

        // PV: O_un[q][d] += P[q][j] * V[j][d]
        __builtin_amdgcn_s_setprio(1);
#pragma unroll
        for (int f = 0; f < 2; ++f)
#pragma unroll
            for (int g = 0; g < 2; ++g)
                oacc[g] = __builtin_amdgcn_mfma_f32_32x32x16_bf16(pa[f], vstage[cur][vslot[f][g]], oacc[g], 0, 0, 0);
        __builtin_amdgcn_s_setprio(0);

        // (c) write tile t+1 staged regs into buf nxt (safe: its readers
        //     finished at the barrier two iterations ago)
        if ((t + 1) < NT) {
            kstage[nxt][sslot] = cvt8(k1a, k1b);
            bf16x8 vv;
#pragma unroll
            for (int k = 0; k < 8; ++k) vv[k] = (__bf16)v1[k];
            vstage[nxt][vwslot] = vv;
        }
        __syncthreads();

        // (d) shift prefetch regs
        k1a = k2a; k1b = k2b;
#pragma unroll
        for (int k = 0; k < 8; ++k) v1[k] = v2[k];
        cur = nxt;
    }

    // row-sum inverse; lane holds q-row l31 (halves hold partial sums)
    const float ssum = (sums4[0] + sums4[1]) + (sums4[2] + sums4[3]);
    const float inv = 1.0f / (ssum + __shfl_xor(ssum, 32));
    float invq[16];
#pragma unroll
    for (int r = 0; r < 16; ++r)
        invq[r] = __shfl(inv, (r & 3) + 8 * (r >> 2) + 4 * h2);

    // O write, normalized (C layout: row=q, col=d=l31+32g)
#pragma unroll
    for (int g = 0; g < 2; ++g)
#pragma unroll
        for (int r = 0; r < 16; ++r) {
            const int qr = (r & 3) + 8 * (r >> 2) + 4 * h2;
            __builtin_nontemporal_store(oacc[g][r] * invq[r],
                                        &orow[(size_t)qr * D + 32 * g + l31]);
        }

    // =============== Pass 2: attention write (lean, double-buffered) ===============
    {
        const float4* p4 = (const float4*)ksrc;
        kstage[0][sslot] = cvt8(p4[0], p4[1]);
    }
    __syncthreads();

    cur = 0;
    for (int j0 = 0; j0 < S; j0 += 32) {
        const bool more = (j0 + 32) < S;
        float4 kna{}, knb{};
        if (more) {
            const float4* p4 = (const float4*)(ksrc + (size_t)(j0 + 32) * D);
            kna = p4[0]; knb = p4[1];
        }
        const bool mf = (mlds[j0 >> 5] >> l31) & 1;

        // normal QK^T: C[row=q][col=j], lane col = j = l31 -> coalesced stores
        f32x16 acc;
#pragma unroll
        for (int r = 0; r < 16; ++r) acc[r] = 0.f;
        __builtin_amdgcn_s_setprio(1);
#pragma unroll
        for (int u = 0; u < 4; ++u)
            acc = __builtin_amdgcn_mfma_f32_32x32x16_bf16(qa[u], kstage[cur][kslot[u]], acc, 0, 0, 0);
        __builtin_amdgcn_s_setprio(0);

#pragma unroll
        for (int r = 0; r < 16; ++r) {
            float p = mf ? fexp2(acc[r]) : 1.0f;
            p *= invq[r];
            const int qr = (r & 3) + 8 * (r >> 2) + 4 * h2;
            __builtin_nontemporal_store(p, &att[(size_t)qr * S + j0 + l31]);
        }
        if (more) kstage[cur ^ 1][sslot] = cvt8(kna, knb);
        __syncthreads();
        cur ^= 1;
    }
}

extern "C" void kernel_launch(void* const* d_in, const int* in_sizes, int n_in,
                              void* d_out, int out_size, void* d_ws, size_t ws_size,
                              hipStream_t stream) {
    const float* q    = (const float*)d_in[0];
    const float* k    = (const float*)d_in[1];
    const float* v    = (const float*)d_in[2];
    const int*   mask = (const int*)d_in[3];
    float* out = (float*)d_out;                       // [B,H,S,D] output first
    float* att = out + (size_t)64 * S * D;            // then [B,H,S,S] attention
    hipLaunchKernelGGL(attn_fused, dim3(1024), dim3(256), 0, stream,
                       q, k, v, mask, out, att);
}